// Round 7
// baseline (685.554 us; speedup 1.0000x reference)
//
#include <hip/hip_runtime.h>

#define NBATCH  131072
#define THREADS 128
#define BPB     16
#define NBLOCKS (NBATCH / BPB)     // 8192

typedef __attribute__((ext_vector_type(8))) _Float16 half8;
typedef __attribute__((ext_vector_type(4))) float f32x4;

// LDS (bytes):
//  [0, 19200):      sxT f16 [16 batches][15 pos][80B row: 64B = 32 ch (21 data + 11 zero), 16B pad]
//                   -> stage 3 reuses [0, 14080) as out staging f32 [16][220 dw]
//  [19200, 20288):  lbuf f32 [16][17]  logit exchange
#define Y_RS 80
#define Y_BS 1200
#define LB_OFF 19200
#define SMEM_BYTES 20288
#define OUT_SDW 220

static __device__ __forceinline__ unsigned short f2h(float f) {
    return __builtin_bit_cast(unsigned short, (_Float16)f);   // RNE
}
static __device__ __forceinline__ unsigned int pack2h(float a, float b) {
    return (unsigned int)f2h(a) | ((unsigned int)f2h(b) << 16);
}

// ---- conv0 via MFMA + attention softmax; h in regs; y written in-place to sxT ----
template<int P0, int NP>
__device__ __forceinline__ void conv0_att(char* sxT, float* lbuf,
        const half8 (&af0)[2],
        const float* __restrict__ attw, const float* __restrict__ attb,
        int col, int g, int lane) {
    f32x4 h[NP][2];
    #pragma unroll
    for (int i = 0; i < NP; ++i) {
        const int p = P0 + i;
        half8 bf = *(const half8*)(sxT + col * Y_BS + p * Y_RS + g * 16);
        const f32x4 z = {0.f, 0.f, 0.f, 0.f};
        h[i][0] = __builtin_amdgcn_mfma_f32_16x16x32_f16(af0[0], bf, z, 0, 0, 0);
        h[i][1] = __builtin_amdgcn_mfma_f32_16x16x32_f16(af0[1], bf, z, 0, 0, 0);
        float4 a0 = *(const float4*)(attw + p * 32 + 4 * g);
        float4 a1 = *(const float4*)(attw + p * 32 + 16 + 4 * g);
        float lp = h[i][0][0] * a0.x;
        lp = fmaf(h[i][0][1], a0.y, lp); lp = fmaf(h[i][0][2], a0.z, lp);
        lp = fmaf(h[i][0][3], a0.w, lp); lp = fmaf(h[i][1][0], a1.x, lp);
        lp = fmaf(h[i][1][1], a1.y, lp); lp = fmaf(h[i][1][2], a1.z, lp);
        lp = fmaf(h[i][1][3], a1.w, lp);
        lp += __shfl_xor(lp, 16, 64);
        lp += __shfl_xor(lp, 32, 64);
        lp += attb[p];
        if (lane < 16) lbuf[lane * 17 + p] = lp;
    }
    __syncthreads();    // all 15 logits visible; all conv0 x-reads complete
    float lg[15];
    #pragma unroll
    for (int l = 0; l < 15; ++l) lg[l] = lbuf[col * 17 + l];
    float mx = lg[0];
    #pragma unroll
    for (int l = 1; l < 15; ++l) mx = fmaxf(mx, lg[l]);
    float e[15], sum = 0.f;
    #pragma unroll
    for (int l = 0; l < 15; ++l) { e[l] = __expf(lg[l] - mx); sum += e[l]; }
    const float inv = 1.f / sum;
    #pragma unroll
    for (int i = 0; i < NP; ++i) {
        const int p = P0 + i;
        const float s = e[p] * inv;
        uint2 u0, u1;
        u0.x = pack2h(h[i][0][0] * s, h[i][0][1] * s);
        u0.y = pack2h(h[i][0][2] * s, h[i][0][3] * s);
        u1.x = pack2h(h[i][1][0] * s, h[i][1][1] * s);
        u1.y = pack2h(h[i][1][2] * s, h[i][1][3] * s);
        char* yr = sxT + col * Y_BS + p * Y_RS;
        *(uint2*)(yr + 8 * g) = u0;          // channels 4g..4g+3
        *(uint2*)(yr + 32 + 8 * g) = u1;     // channels 16+4g..19+4g
    }
}

// ---- conv1(+bn1+lrelu) -> reg fragments -> conv2(+bn2+lrelu) -> out staging ----
// conv1 C-rows carry permuted channels chan1(mt,row)=32(mt>>1)+8(row>>2)+4(mt&1)+(row&3)
// so each lane's accumulators are exactly its conv2 B-fragment k-slices.
template<int R0, int NR, int P0, int NP>
__device__ __forceinline__ void stack23(
    char* __restrict__ sxT, const int col, const int g,
    const float* __restrict__ w1, const float* __restrict__ cb1,
    const float* __restrict__ g1, const float* __restrict__ bt1,
    const float* __restrict__ mn1, const float* __restrict__ vr1,
    const float* __restrict__ w2, const float* __restrict__ cb2,
    const float* __restrict__ g2, const float* __restrict__ bt2,
    const float* __restrict__ mn2, const float* __restrict__ vr2)
{
    float* sout = (float*)sxT;
    // conv1 A-fragments (bn scale folded) + shifts
    half8 af2[4][3];
    #pragma unroll
    for (int mt = 0; mt < 4; ++mt) {
        const int o = 32*(mt>>1) + 8*(col>>2) + 4*(mt&1) + (col&3);
        const float iva = g1[o] * rsqrtf(vr1[o] + 1e-5f);
        const float* wp = w1 + o*96 + g*24;
        float f[24];
        #pragma unroll
        for (int q = 0; q < 6; ++q) {
            float4 v = *(const float4*)(wp + 4*q);
            f[4*q+0]=v.x; f[4*q+1]=v.y; f[4*q+2]=v.z; f[4*q+3]=v.w;
        }
        #pragma unroll
        for (int s = 0; s < 3; ++s) {
            half8 fh;
            #pragma unroll
            for (int j = 0; j < 8; ++j) fh[j] = (_Float16)(f[j*3+s] * iva);
            af2[mt][s] = fh;
        }
    }
    float sha1v[16];
    #pragma unroll
    for (int mt = 0; mt < 4; ++mt)
    #pragma unroll
    for (int r = 0; r < 4; ++r) {
        const int o = 32*(mt>>1) + 8*g + 4*(mt&1) + r;
        const float iva = g1[o] * rsqrtf(vr1[o] + 1e-5f);
        sha1v[mt*4+r] = bt1[o] + (cb1[o] - mn1[o]) * iva;
    }

    // row phase: a1 rows R0..R0+NR-1 -> fr register fragments
    half8 fr[NR][2];
    {
        const char* yb = sxT + col * Y_BS;
        half8 y3[3];
        y3[(R0 + 0) % 3] = *(const half8*)(yb + (R0 + 0) * Y_RS + g * 16);
        y3[(R0 + 1) % 3] = *(const half8*)(yb + (R0 + 1) * Y_RS + g * 16);
        #pragma unroll
        for (int i = 0; i < NR; ++i) {
            const int r = R0 + i;
            y3[(r + 2) % 3] = *(const half8*)(yb + (r + 2) * Y_RS + g * 16);
            f32x4 a0 = {0.f,0.f,0.f,0.f}, a1 = {0.f,0.f,0.f,0.f};
            f32x4 a2 = {0.f,0.f,0.f,0.f}, a3 = {0.f,0.f,0.f,0.f};
            #pragma unroll
            for (int s = 0; s < 3; ++s) {
                const half8 yy = y3[(r + s) % 3];
                a0 = __builtin_amdgcn_mfma_f32_16x16x32_f16(af2[0][s], yy, a0, 0,0,0);
                a1 = __builtin_amdgcn_mfma_f32_16x16x32_f16(af2[1][s], yy, a1, 0,0,0);
                a2 = __builtin_amdgcn_mfma_f32_16x16x32_f16(af2[2][s], yy, a2, 0,0,0);
                a3 = __builtin_amdgcn_mfma_f32_16x16x32_f16(af2[3][s], yy, a3, 0,0,0);
            }
            float z[4][4];
            #pragma unroll
            for (int r2 = 0; r2 < 4; ++r2) {
                float t0 = a0[r2] + sha1v[ 0+r2]; z[0][r2] = fmaxf(t0, 0.01f*t0);
                float t1 = a1[r2] + sha1v[ 4+r2]; z[1][r2] = fmaxf(t1, 0.01f*t1);
                float t2 = a2[r2] + sha1v[ 8+r2]; z[2][r2] = fmaxf(t2, 0.01f*t2);
                float t3 = a3[r2] + sha1v[12+r2]; z[3][r2] = fmaxf(t3, 0.01f*t3);
            }
            uint4 u0, u1;
            u0.x = pack2h(z[0][0], z[0][1]); u0.y = pack2h(z[0][2], z[0][3]);
            u0.z = pack2h(z[1][0], z[1][1]); u0.w = pack2h(z[1][2], z[1][3]);
            u1.x = pack2h(z[2][0], z[2][1]); u1.y = pack2h(z[2][2], z[2][3]);
            u1.z = pack2h(z[3][0], z[3][1]); u1.w = pack2h(z[3][2], z[3][3]);
            fr[i][0] = __builtin_bit_cast(half8, u0);
            fr[i][1] = __builtin_bit_cast(half8, u1);
        }
    }
    __syncthreads();   // all y reads done before out staging overwrites sxT

    // conv2 A-fragments
    half8 af3[2][6];
    float iva2v[2];
    #pragma unroll
    for (int mt = 0; mt < 2; ++mt) {
        const int o = mt * 16 + col;
        iva2v[mt] = (o < 20) ? g2[o] * rsqrtf(vr2[o] + 1e-5f) : 0.f;
        if (o < 20) {
            const float iva = iva2v[mt];
            #pragma unroll
            for (int hh = 0; hh < 2; ++hh) {
                const float* wp = w2 + o*192 + hh*96 + g*24;
                float f[24];
                #pragma unroll
                for (int q = 0; q < 6; ++q) {
                    float4 v = *(const float4*)(wp + 4*q);
                    f[4*q+0]=v.x; f[4*q+1]=v.y; f[4*q+2]=v.z; f[4*q+3]=v.w;
                }
                #pragma unroll
                for (int tap = 0; tap < 3; ++tap) {
                    half8 fh;
                    #pragma unroll
                    for (int j = 0; j < 8; ++j) fh[j] = (_Float16)(f[j*3+tap] * iva);
                    af3[mt][tap*2 + hh] = fh;
                }
            }
        } else {
            #pragma unroll
            for (int s = 0; s < 6; ++s) {
                half8 zf;
                #pragma unroll
                for (int j = 0; j < 8; ++j) zf[j] = (_Float16)0.f;
                af3[mt][s] = zf;
            }
        }
    }
    float sha2v[8];
    #pragma unroll
    for (int mt = 0; mt < 2; ++mt)
    #pragma unroll
    for (int r = 0; r < 4; ++r) {
        const int o = mt*16 + 4*g + r;
        if (o < 20) {
            const float iva = g2[o] * rsqrtf(vr2[o] + 1e-5f);
            sha2v[mt*4+r] = bt2[o] + (cb2[o] - mn2[o]) * iva;
        } else sha2v[mt*4+r] = 0.f;
    }

    #pragma unroll
    for (int pp = 0; pp < NP; ++pp) {
        const int p = P0 + pp;
        f32x4 acc0 = {0.f,0.f,0.f,0.f}, acc1 = {0.f,0.f,0.f,0.f};
        #pragma unroll
        for (int s = 0; s < 6; ++s) {
            const half8 bb = fr[pp + (s >> 1)][s & 1];
            acc0 = __builtin_amdgcn_mfma_f32_16x16x32_f16(af3[0][s], bb, acc0, 0,0,0);
            acc1 = __builtin_amdgcn_mfma_f32_16x16x32_f16(af3[1][s], bb, acc1, 0,0,0);
        }
        #pragma unroll
        for (int r = 0; r < 4; ++r) {
            float t0 = acc0[r] + sha2v[r];
            t0 = fmaxf(t0, 0.01f*t0);
            sout[col*OUT_SDW + (4*g + r)*11 + p] = t0;
        }
        if (g == 0) {
            #pragma unroll
            for (int r = 0; r < 4; ++r) {
                float t1 = acc1[r] + sha2v[4+r];
                t1 = fmaxf(t1, 0.01f*t1);
                sout[col*OUT_SDW + (16 + r)*11 + p] = t1;
            }
        }
    }
}

__global__ __launch_bounds__(THREADS, 4)
void peptide_v7(const float* __restrict__ x,
                const float* __restrict__ w0,     // [32][21]
                const float* __restrict__ attw,   // [15][32]
                const float* __restrict__ attb,   // [15]
                const float* __restrict__ w1,     // [64][32][3]
                const float* __restrict__ cb1,
                const float* __restrict__ g1, const float* __restrict__ bt1,
                const float* __restrict__ mn1, const float* __restrict__ vr1,
                const float* __restrict__ w2,     // [20][64][3]
                const float* __restrict__ cb2,
                const float* __restrict__ g2, const float* __restrict__ bt2,
                const float* __restrict__ mn2, const float* __restrict__ vr2,
                float* __restrict__ out)          // [B][20][11]
{
    __shared__ __align__(16) char smem[SMEM_BYTES];
    char*  sxT  = smem;
    float* lbuf = (float*)(smem + LB_OFF);

    const int tid  = threadIdx.x;
    const int lane = tid & 63;
    const int wv   = tid >> 6;
    const int col  = lane & 15;
    const int g    = lane >> 4;

    // ---- gather-transpose: global x [b][c][p] -> sxT f16 [b][p][c, zero-pad to 32] ----
    {
        const float* xg = x + (size_t)blockIdx.x * (BPB * 315);
        #pragma unroll
        for (int q = 0; q < 2; ++q) {
            const int u = q * THREADS + tid;          // (b,p) task
            if (u < 240) {
                const int b = (int)(((unsigned)u * 4370u) >> 16);   // u / 15
                const int p = u - b * 15;
                const float* src = xg + b * 315 + p;
                float v[21];
                #pragma unroll
                for (int c = 0; c < 21; ++c) v[c] = src[c * 15];
                uint4 d0, d1, d2, d3;
                d0.x = pack2h(v[0],  v[1]);  d0.y = pack2h(v[2],  v[3]);
                d0.z = pack2h(v[4],  v[5]);  d0.w = pack2h(v[6],  v[7]);
                d1.x = pack2h(v[8],  v[9]);  d1.y = pack2h(v[10], v[11]);
                d1.z = pack2h(v[12], v[13]); d1.w = pack2h(v[14], v[15]);
                d2.x = pack2h(v[16], v[17]); d2.y = pack2h(v[18], v[19]);
                d2.z = pack2h(v[20], 0.f);   d2.w = 0u;
                d3.x = 0u; d3.y = 0u; d3.z = 0u; d3.w = 0u;
                char* dst = sxT + b * Y_BS + p * Y_RS;
                *(uint4*)(dst)      = d0;
                *(uint4*)(dst + 16) = d1;
                *(uint4*)(dst + 32) = d2;
                *(uint4*)(dst + 48) = d3;
            }
        }
    }

    // conv0 A-fragments (natural channel rows; c>=21 zeroed)
    half8 af0[2];
    #pragma unroll
    for (int mt = 0; mt < 2; ++mt) {
        const int o = mt * 16 + col;
        #pragma unroll
        for (int j = 0; j < 8; ++j) {
            const int c = 8 * g + j;
            af0[mt][j] = (c < 21) ? (_Float16)w0[o * 21 + c] : (_Float16)0.f;
        }
    }
    __syncthreads();                      // xT ready

    // ---- conv0 MFMA + attention softmax (y in-place) ----
    if (wv == 0) conv0_att<0, 8>(sxT, lbuf, af0, attw, attb, col, g, lane);
    else         conv0_att<8, 7>(sxT, lbuf, af0, attw, attb, col, g, lane);
    __syncthreads();                      // y complete (cross-wave rows)

    // ---- conv1 -> regs -> conv2 -> out staging ----
    if (wv == 0) stack23<0, 8, 0, 6>(sxT, col, g, w1, cb1, g1, bt1, mn1, vr1,
                                     w2, cb2, g2, bt2, mn2, vr2);
    else         stack23<6, 7, 6, 5>(sxT, col, g, w1, cb1, g1, bt1, mn1, vr1,
                                     w2, cb2, g2, bt2, mn2, vr2);
    __syncthreads();                      // out staging complete

    // ---- gap-free coalesced copy-out: 16 x 220 dw = one 14080 B span ----
    {
        float* ob = out + (size_t)blockIdx.x * (BPB * 220);
        const float* sf = (const float*)sxT;
        #pragma unroll
        for (int j = 0; j < 7; ++j) {
            const int u = j * THREADS + tid;          // 16B unit
            if (u < 880) {
                f32x4 v = *(const f32x4*)(sf + u * 4);
                *(f32x4*)(ob + u * 4) = v;
            }
        }
    }
}

extern "C" void kernel_launch(void* const* d_in, const int* in_sizes, int n_in,
                              void* d_out, int out_size, void* d_ws, size_t ws_size,
                              hipStream_t stream) {
    const float* x    = (const float*)d_in[0];
    const float* w0   = (const float*)d_in[1];
    const float* attw = (const float*)d_in[2];
    const float* attb = (const float*)d_in[3];
    const float* w1   = (const float*)d_in[4];
    const float* cb1  = (const float*)d_in[5];
    const float* g1   = (const float*)d_in[6];
    const float* bt1  = (const float*)d_in[7];
    const float* mn1  = (const float*)d_in[8];
    const float* vr1  = (const float*)d_in[9];
    const float* w2   = (const float*)d_in[10];
    const float* cb2  = (const float*)d_in[11];
    const float* g2   = (const float*)d_in[12];
    const float* bt2  = (const float*)d_in[13];
    const float* mn2  = (const float*)d_in[14];
    const float* vr2  = (const float*)d_in[15];

    dim3 grid(NBLOCKS);
    dim3 block(THREADS);
    hipLaunchKernelGGL(peptide_v7, grid, block, 0, stream,
                       x, w0, attw, attb,
                       w1, cb1, g1, bt1, mn1, vr1,
                       w2, cb2, g2, bt2, mn2, vr2,
                       (float*)d_out);
}

// Round 8
// 237.635 us; speedup vs baseline: 2.8849x; 2.8849x over previous
//
#include <hip/hip_runtime.h>

#define NBATCH  131072
#define THREADS 128
#define BPB     16
#define NBLOCKS (NBATCH / BPB)     // 8192

typedef __attribute__((ext_vector_type(8))) _Float16 half8;
typedef __attribute__((ext_vector_type(4))) float f32x4;

// LDS (bytes):
//  [0, 19200):      sxT f16 [16 b][15 p][80B: 64B = ch 0..31 (21 data + 11 zero), 16B pad]
//                   stage2/3 writes y in place; stage3 reuses [0,14080) as out f32 [16][220]
//  [19200, 20480):  lbuf f32 [16][20]   logit exchange (rows 16B-aligned)
#define Y_RS 80
#define Y_BS 1200
#define LB_OFF 19200
#define SMEM_BYTES 20480
#define OUT_SDW 220

static __device__ __forceinline__ unsigned short f2h(float f) {
    return __builtin_bit_cast(unsigned short, (_Float16)f);   // RNE
}
static __device__ __forceinline__ unsigned int pack2h(float a, float b) {
    return (unsigned int)f2h(a) | ((unsigned int)f2h(b) << 16);
}
static __device__ __forceinline__ half8 splat8(float s) {
    const _Float16 h = (_Float16)s;
    half8 v;
    #pragma unroll
    for (int j = 0; j < 8; ++j) v[j] = h;
    return v;
}

// ---- conv0 via MFMA + attention softmax; h packed f16 in regs; y in-place to sxT ----
template<int P0, int NP>
__device__ __forceinline__ void conv0_att(char* sxT, float* lbuf,
        const half8 (&af0)[2],
        const float* __restrict__ attw, const float* __restrict__ attb,
        int col, int g, int lane) {
    half8 hq[NP];                      // packed h: {ch 4g..4g+3, 16+4g..19+4g}
    #pragma unroll
    for (int i = 0; i < NP; ++i) {
        const int p = P0 + i;
        half8 bf = *(const half8*)(sxT + col * Y_BS + p * Y_RS + g * 16);
        const f32x4 z = {0.f, 0.f, 0.f, 0.f};
        f32x4 h0 = __builtin_amdgcn_mfma_f32_16x16x32_f16(af0[0], bf, z, 0, 0, 0);
        f32x4 h1 = __builtin_amdgcn_mfma_f32_16x16x32_f16(af0[1], bf, z, 0, 0, 0);
        float4 a0 = *(const float4*)(attw + p * 32 + 4 * g);
        float4 a1 = *(const float4*)(attw + p * 32 + 16 + 4 * g);
        float lp = h0[0] * a0.x;
        lp = fmaf(h0[1], a0.y, lp); lp = fmaf(h0[2], a0.z, lp);
        lp = fmaf(h0[3], a0.w, lp); lp = fmaf(h1[0], a1.x, lp);
        lp = fmaf(h1[1], a1.y, lp); lp = fmaf(h1[2], a1.z, lp);
        lp = fmaf(h1[3], a1.w, lp);
        lp += __shfl_xor(lp, 16, 64);
        lp += __shfl_xor(lp, 32, 64);
        if (lane < 16) lbuf[col * 20 + p] = lp + attb[p];
        uint4 u;
        u.x = pack2h(h0[0], h0[1]); u.y = pack2h(h0[2], h0[3]);
        u.z = pack2h(h1[0], h1[1]); u.w = pack2h(h1[2], h1[3]);
        hq[i] = __builtin_bit_cast(half8, u);
    }
    __syncthreads();    // all 15 logits visible; all conv0 x-reads complete
    const float* lb = lbuf + col * 20;
    float4 l0 = *(const float4*)(lb + 0);
    float4 l1 = *(const float4*)(lb + 4);
    float4 l2 = *(const float4*)(lb + 8);
    float4 l3 = *(const float4*)(lb + 12);      // .w is garbage, unused
    float lg[15] = {l0.x,l0.y,l0.z,l0.w, l1.x,l1.y,l1.z,l1.w,
                    l2.x,l2.y,l2.z,l2.w, l3.x,l3.y,l3.z};
    float mx = lg[0];
    #pragma unroll
    for (int l = 1; l < 15; ++l) mx = fmaxf(mx, lg[l]);
    float e[15], sum = 0.f;
    #pragma unroll
    for (int l = 0; l < 15; ++l) { e[l] = __expf(lg[l] - mx); sum += e[l]; }
    const float inv = 1.f / sum;
    #pragma unroll
    for (int i = 0; i < NP; ++i) {
        const int p = P0 + i;
        half8 ys = hq[i] * splat8(e[p] * inv);   // v_pk_mul_f16
        uint4 u = __builtin_bit_cast(uint4, ys);
        char* yr = sxT + col * Y_BS + p * Y_RS;
        uint2 u0; u0.x = u.x; u0.y = u.y;
        uint2 u1; u1.x = u.z; u1.y = u.w;
        *(uint2*)(yr + 8 * g) = u0;              // channels 4g..4g+3
        *(uint2*)(yr + 32 + 8 * g) = u1;         // channels 16+4g..19+4g
    }
}

// ---- conv1(+bn1+lrelu) -> reg fragments -> conv2(+bn2+lrelu) -> out staging ----
// conv1 C-rows carry permuted channels chan1(mt,row)=32(mt>>1)+8(row>>2)+4(mt&1)+(row&3)
// so each lane's accumulators are exactly its conv2 B-fragment k-slices.
template<int R0, int NR, int P0, int NP>
__device__ __forceinline__ void stack23(
    char* __restrict__ sxT, const int col, const int g,
    const float* __restrict__ w1, const float* __restrict__ cb1,
    const float* __restrict__ g1, const float* __restrict__ bt1,
    const float* __restrict__ mn1, const float* __restrict__ vr1,
    const float* __restrict__ w2, const float* __restrict__ cb2,
    const float* __restrict__ g2, const float* __restrict__ bt2,
    const float* __restrict__ mn2, const float* __restrict__ vr2)
{
    float* sout = (float*)sxT;
    half8 af2[4][3];
    #pragma unroll
    for (int mt = 0; mt < 4; ++mt) {
        const int o = 32*(mt>>1) + 8*(col>>2) + 4*(mt&1) + (col&3);
        const float iva = g1[o] * rsqrtf(vr1[o] + 1e-5f);
        const float* wp = w1 + o*96 + g*24;
        float f[24];
        #pragma unroll
        for (int q = 0; q < 6; ++q) {
            float4 v = *(const float4*)(wp + 4*q);
            f[4*q+0]=v.x; f[4*q+1]=v.y; f[4*q+2]=v.z; f[4*q+3]=v.w;
        }
        #pragma unroll
        for (int s = 0; s < 3; ++s) {
            half8 fh;
            #pragma unroll
            for (int j = 0; j < 8; ++j) fh[j] = (_Float16)(f[j*3+s] * iva);
            af2[mt][s] = fh;
        }
    }
    float sha1v[16];
    #pragma unroll
    for (int mt = 0; mt < 4; ++mt)
    #pragma unroll
    for (int r = 0; r < 4; ++r) {
        const int o = 32*(mt>>1) + 8*g + 4*(mt&1) + r;
        const float iva = g1[o] * rsqrtf(vr1[o] + 1e-5f);
        sha1v[mt*4+r] = bt1[o] + (cb1[o] - mn1[o]) * iva;
    }

    half8 fr[NR][2];
    {
        const char* yb = sxT + col * Y_BS;
        half8 y3[3];
        y3[(R0 + 0) % 3] = *(const half8*)(yb + (R0 + 0) * Y_RS + g * 16);
        y3[(R0 + 1) % 3] = *(const half8*)(yb + (R0 + 1) * Y_RS + g * 16);
        #pragma unroll
        for (int i = 0; i < NR; ++i) {
            const int r = R0 + i;
            y3[(r + 2) % 3] = *(const half8*)(yb + (r + 2) * Y_RS + g * 16);
            f32x4 a0 = {0.f,0.f,0.f,0.f}, a1 = {0.f,0.f,0.f,0.f};
            f32x4 a2 = {0.f,0.f,0.f,0.f}, a3 = {0.f,0.f,0.f,0.f};
            #pragma unroll
            for (int s = 0; s < 3; ++s) {
                const half8 yy = y3[(r + s) % 3];
                a0 = __builtin_amdgcn_mfma_f32_16x16x32_f16(af2[0][s], yy, a0, 0,0,0);
                a1 = __builtin_amdgcn_mfma_f32_16x16x32_f16(af2[1][s], yy, a1, 0,0,0);
                a2 = __builtin_amdgcn_mfma_f32_16x16x32_f16(af2[2][s], yy, a2, 0,0,0);
                a3 = __builtin_amdgcn_mfma_f32_16x16x32_f16(af2[3][s], yy, a3, 0,0,0);
            }
            float z[4][4];
            #pragma unroll
            for (int r2 = 0; r2 < 4; ++r2) {
                float t0 = a0[r2] + sha1v[ 0+r2]; z[0][r2] = fmaxf(t0, 0.01f*t0);
                float t1 = a1[r2] + sha1v[ 4+r2]; z[1][r2] = fmaxf(t1, 0.01f*t1);
                float t2 = a2[r2] + sha1v[ 8+r2]; z[2][r2] = fmaxf(t2, 0.01f*t2);
                float t3 = a3[r2] + sha1v[12+r2]; z[3][r2] = fmaxf(t3, 0.01f*t3);
            }
            uint4 u0, u1;
            u0.x = pack2h(z[0][0], z[0][1]); u0.y = pack2h(z[0][2], z[0][3]);
            u0.z = pack2h(z[1][0], z[1][1]); u0.w = pack2h(z[1][2], z[1][3]);
            u1.x = pack2h(z[2][0], z[2][1]); u1.y = pack2h(z[2][2], z[2][3]);
            u1.z = pack2h(z[3][0], z[3][1]); u1.w = pack2h(z[3][2], z[3][3]);
            fr[i][0] = __builtin_bit_cast(half8, u0);
            fr[i][1] = __builtin_bit_cast(half8, u1);
        }
    }
    __syncthreads();   // all y reads done before out staging overwrites sxT

    half8 af3[2][6];
    #pragma unroll
    for (int mt = 0; mt < 2; ++mt) {
        const int o = mt * 16 + col;
        if (o < 20) {
            const float iva = g2[o] * rsqrtf(vr2[o] + 1e-5f);
            #pragma unroll
            for (int hh = 0; hh < 2; ++hh) {
                const float* wp = w2 + o*192 + hh*96 + g*24;
                float f[24];
                #pragma unroll
                for (int q = 0; q < 6; ++q) {
                    float4 v = *(const float4*)(wp + 4*q);
                    f[4*q+0]=v.x; f[4*q+1]=v.y; f[4*q+2]=v.z; f[4*q+3]=v.w;
                }
                #pragma unroll
                for (int tap = 0; tap < 3; ++tap) {
                    half8 fh;
                    #pragma unroll
                    for (int j = 0; j < 8; ++j) fh[j] = (_Float16)(f[j*3+tap] * iva);
                    af3[mt][tap*2 + hh] = fh;
                }
            }
        } else {
            #pragma unroll
            for (int s = 0; s < 6; ++s) {
                half8 zf;
                #pragma unroll
                for (int j = 0; j < 8; ++j) zf[j] = (_Float16)0.f;
                af3[mt][s] = zf;
            }
        }
    }
    float sha2v[8];
    #pragma unroll
    for (int mt = 0; mt < 2; ++mt)
    #pragma unroll
    for (int r = 0; r < 4; ++r) {
        const int o = mt*16 + 4*g + r;
        if (o < 20) {
            const float iva = g2[o] * rsqrtf(vr2[o] + 1e-5f);
            sha2v[mt*4+r] = bt2[o] + (cb2[o] - mn2[o]) * iva;
        } else sha2v[mt*4+r] = 0.f;
    }

    #pragma unroll
    for (int pp = 0; pp < NP; ++pp) {
        const int p = P0 + pp;
        f32x4 acc0 = {0.f,0.f,0.f,0.f}, acc1 = {0.f,0.f,0.f,0.f};
        #pragma unroll
        for (int s = 0; s < 6; ++s) {
            const half8 bb = fr[pp + (s >> 1)][s & 1];
            acc0 = __builtin_amdgcn_mfma_f32_16x16x32_f16(af3[0][s], bb, acc0, 0,0,0);
            acc1 = __builtin_amdgcn_mfma_f32_16x16x32_f16(af3[1][s], bb, acc1, 0,0,0);
        }
        #pragma unroll
        for (int r = 0; r < 4; ++r) {
            float t0 = acc0[r] + sha2v[r];
            t0 = fmaxf(t0, 0.01f*t0);
            sout[col*OUT_SDW + (4*g + r)*11 + p] = t0;
        }
        if (g == 0) {
            #pragma unroll
            for (int r = 0; r < 4; ++r) {
                float t1 = acc1[r] + sha2v[4+r];
                t1 = fmaxf(t1, 0.01f*t1);
                sout[col*OUT_SDW + (16 + r)*11 + p] = t1;
            }
        }
    }
}

__global__ __launch_bounds__(THREADS, 2)
void peptide_v8(const float* __restrict__ x,
                const float* __restrict__ w0,     // [32][21]
                const float* __restrict__ attw,   // [15][32]
                const float* __restrict__ attb,   // [15]
                const float* __restrict__ w1,     // [64][32][3]
                const float* __restrict__ cb1,
                const float* __restrict__ g1, const float* __restrict__ bt1,
                const float* __restrict__ mn1, const float* __restrict__ vr1,
                const float* __restrict__ w2,     // [20][64][3]
                const float* __restrict__ cb2,
                const float* __restrict__ g2, const float* __restrict__ bt2,
                const float* __restrict__ mn2, const float* __restrict__ vr2,
                float* __restrict__ out)          // [B][20][11]
{
    __shared__ __align__(16) char smem[SMEM_BYTES];
    char*  sxT  = smem;
    float* lbuf = (float*)(smem + LB_OFF);

    const int tid  = threadIdx.x;
    const int lane = tid & 63;
    const int wv   = tid >> 6;
    const int col  = lane & 15;
    const int g    = lane >> 4;

    // ---- gather-transpose: global x [b][c][p] -> sxT f16 [b][p][c, zero-pad to 32] ----
    {
        const float* xg = x + (size_t)blockIdx.x * (BPB * 315);
        #pragma unroll
        for (int q = 0; q < 2; ++q) {
            const int u = q * THREADS + tid;          // (b,p) task
            if (u < 240) {
                const int b = (int)(((unsigned)u * 4370u) >> 16);   // u / 15
                const int p = u - b * 15;
                const float* src = xg + b * 315 + p;
                float v[21];
                #pragma unroll
                for (int c = 0; c < 21; ++c) v[c] = src[c * 15];
                uint4 d0, d1, d2, d3;
                d0.x = pack2h(v[0],  v[1]);  d0.y = pack2h(v[2],  v[3]);
                d0.z = pack2h(v[4],  v[5]);  d0.w = pack2h(v[6],  v[7]);
                d1.x = pack2h(v[8],  v[9]);  d1.y = pack2h(v[10], v[11]);
                d1.z = pack2h(v[12], v[13]); d1.w = pack2h(v[14], v[15]);
                d2.x = pack2h(v[16], v[17]); d2.y = pack2h(v[18], v[19]);
                d2.z = pack2h(v[20], 0.f);   d2.w = 0u;
                d3.x = 0u; d3.y = 0u; d3.z = 0u; d3.w = 0u;
                char* dst = sxT + b * Y_BS + p * Y_RS;
                *(uint4*)(dst)      = d0;
                *(uint4*)(dst + 16) = d1;
                *(uint4*)(dst + 32) = d2;
                *(uint4*)(dst + 48) = d3;
            }
        }
    }

    // conv0 A-fragments (rows = channels, k-pad zeroed)
    half8 af0[2];
    #pragma unroll
    for (int mt = 0; mt < 2; ++mt) {
        const int o = mt * 16 + col;
        #pragma unroll
        for (int j = 0; j < 8; ++j) {
            const int c = 8 * g + j;
            af0[mt][j] = (c < 21) ? (_Float16)w0[o * 21 + c] : (_Float16)0.f;
        }
    }
    __syncthreads();                      // xT ready

    // ---- conv0 MFMA + attention softmax (y in-place) ----
    if (wv == 0) conv0_att<0, 8>(sxT, lbuf, af0, attw, attb, col, g, lane);
    else         conv0_att<8, 7>(sxT, lbuf, af0, attw, attb, col, g, lane);
    __syncthreads();                      // y complete (cross-wave rows)

    // ---- conv1 -> regs -> conv2 -> out staging ----
    if (wv == 0) stack23<0, 8, 0, 6>(sxT, col, g, w1, cb1, g1, bt1, mn1, vr1,
                                     w2, cb2, g2, bt2, mn2, vr2);
    else         stack23<6, 7, 6, 5>(sxT, col, g, w1, cb1, g1, bt1, mn1, vr1,
                                     w2, cb2, g2, bt2, mn2, vr2);
    __syncthreads();                      // out staging complete

    // ---- gap-free coalesced copy-out: 16 x 220 dw = one 14080 B span ----
    {
        float* ob = out + (size_t)blockIdx.x * (BPB * 220);
        const float* sf = (const float*)sxT;
        #pragma unroll
        for (int j = 0; j < 7; ++j) {
            const int u = j * THREADS + tid;          // 16B unit
            if (u < 880) {
                f32x4 v = *(const f32x4*)(sf + u * 4);
                *(f32x4*)(ob + u * 4) = v;
            }
        }
    }
}

extern "C" void kernel_launch(void* const* d_in, const int* in_sizes, int n_in,
                              void* d_out, int out_size, void* d_ws, size_t ws_size,
                              hipStream_t stream) {
    const float* x    = (const float*)d_in[0];
    const float* w0   = (const float*)d_in[1];
    const float* attw = (const float*)d_in[2];
    const float* attb = (const float*)d_in[3];
    const float* w1   = (const float*)d_in[4];
    const float* cb1  = (const float*)d_in[5];
    const float* g1   = (const float*)d_in[6];
    const float* bt1  = (const float*)d_in[7];
    const float* mn1  = (const float*)d_in[8];
    const float* vr1  = (const float*)d_in[9];
    const float* w2   = (const float*)d_in[10];
    const float* cb2  = (const float*)d_in[11];
    const float* g2   = (const float*)d_in[12];
    const float* bt2  = (const float*)d_in[13];
    const float* mn2  = (const float*)d_in[14];
    const float* vr2  = (const float*)d_in[15];

    dim3 grid(NBLOCKS);
    dim3 block(THREADS);
    hipLaunchKernelGGL(peptide_v8, grid, block, 0, stream,
                       x, w0, attw, attb,
                       w1, cb1, g1, bt1, mn1, vr1,
                       w2, cb2, g2, bt2, mn2, vr2,
                       (float*)d_out);
}